// Round 10
// baseline (296.587 us; speedup 1.0000x reference)
//
#include <hip/hip_runtime.h>
#include <cstdint>
#include <cstddef>

// ---------------------------------------------------------------------------
// NaiveSDPA: out[n,s,v] = softmax(Q·K^T / 8 + mask) · V ; f32 I/O, bf16 MFMA.
// v15: dual-stream waves + DMA images + atomic KV-split.
// r9 pipe model: LDS pipe ~59% busy is the top consumer; single-stream waves
// read the whole K/V tile per 16 q. v6's dual-stream (32 q/wave) halves LDS
// traffic per q and amortizes address VALU over 2 MFMAs; its old cost (32
// staging regs + ls/ones) is gone via r9 DMA images + r8 scalar rs ->
// ~110-125 combined regs, fits the 128 tier (v6 was ~132).
//   - sdpa_fwd_dual: 256 thr, 4 waves x 32q (r0-proven mapping), DMA tiles,
//     KV-split x2 -> grid (32,16,2) = 1024 blocks = 4 blocks/CU = 16
//     waves/CU in FOUR independent barrier groups (1 wave/SIMD per block).
//   - split combine via zero-init + f32 atomicAdd O / L + normalize pass:
//     ws need = images 18.9 MB + L 0.26 MB = 19.1 MB (proven >=34 in r2) —
//     dodges the ws>=53MB uncertainty that blocked r9's Path A.
//   - fallbacks: spill tripwire (hipFuncGetAttributes, r8-proven) ->
//     r9-proven single-pass sdpa_fwd_dma<4> -> reg-staging kernel.
// Predicted: conflicts 2.2e7->1.1e7, fwd 200->135-160us, total ~245-270.
// ---------------------------------------------------------------------------

typedef __attribute__((ext_vector_type(8))) short short8;
typedef __attribute__((ext_vector_type(4))) short short4v;
typedef __attribute__((ext_vector_type(4))) float f32x4;
typedef __attribute__((ext_vector_type(4))) unsigned int uint4v;
typedef __attribute__((ext_vector_type(2))) unsigned int uint2v;

#define DEV __device__ __forceinline__

constexpr int N_B   = 16;
constexpr int S_Q   = 4096;
constexpr int S_KV  = 4096;
constexpr int DH    = 64;
constexpr int BQ    = 128;         // q rows per block
constexpr int BK    = 64;
constexpr int ITERS = S_KV / BK;   // 64 tiles
constexpr int KSTR  = 72;          // shorts/K-row: 144B (skew 4 dwords)
constexpr int VSTR  = 68;          // shorts/V^T-row: 136B (16 slots + pad)
constexpr int KIMG_B = 9216;       // K tile image bytes
constexpr int VIMG_B = 9216;       // V tile image bytes (8704 + 512 pad)
constexpr int TILE_B = KIMG_B + VIMG_B;   // 18432

#define LOG2E 1.44269504088896340736f
#define QSCALE (0.125f * 1.44269504088896340736f)   // fold /8 + log2e into Q

DEV unsigned short f2bf(float f) {           // RNE f32 -> bf16
  union { float f; unsigned int i; } x; x.f = f;
  unsigned int r = x.i + 0x7FFFu + ((x.i >> 16) & 1u);
  return (unsigned short)(r >> 16);
}

#if __has_builtin(__builtin_amdgcn_cvt_pk_bf16_f32)
typedef __attribute__((ext_vector_type(2))) __bf16 bf16x2v;
DEV unsigned int packrne(float a, float b) {   // bf16(a) lo | bf16(b) hi, RNE
  union { bf16x2v v; unsigned int u; } x;
  x.v = __builtin_amdgcn_cvt_pk_bf16_f32(a, b);
  return x.u;
}
#else
DEV unsigned int packrne(float a, float b) {
  union { float f; unsigned int u; } ua, ub; ua.f = a; ub.f = b;
  unsigned int ra = ua.u + 0x7FFFu + ((ua.u >> 16) & 1u);
  unsigned int rb = ub.u + 0x7FFFu + ((ub.u >> 16) & 1u);
  return __builtin_amdgcn_perm(rb, ra, 0x07060302u);
}
#endif

DEV f32x4 mfma16(short4v a, short4v b, f32x4 c) {
#if __has_builtin(__builtin_amdgcn_mfma_f32_16x16x16bf16_1k)
  return __builtin_amdgcn_mfma_f32_16x16x16bf16_1k(a, b, c, 0, 0, 0);
#elif __has_builtin(__builtin_amdgcn_mfma_f32_16x16x16_bf16)
  return __builtin_amdgcn_mfma_f32_16x16x16_bf16(a, b, c, 0, 0, 0);
#else
  asm volatile("v_mfma_f32_16x16x16_bf16 %0, %1, %2, %0\n\ts_nop 7\n\ts_nop 7"
               : "+v"(c) : "v"(a), "v"(b));
  return c;
#endif
}

// stage K tile image (256 threads): thread tS owns 16B chunks
// (r=tS>>3, c=tS&7) and (r+32, c).
DEV void stageK(unsigned short* buf, const f32x4* L, int tS) {
  const int r0 = tS >> 3, c = tS & 7;
  uint4v d0, d1;
  d0[0] = packrne(L[0][0], L[0][1]); d0[1] = packrne(L[0][2], L[0][3]);
  d0[2] = packrne(L[1][0], L[1][1]); d0[3] = packrne(L[1][2], L[1][3]);
  d1[0] = packrne(L[2][0], L[2][1]); d1[1] = packrne(L[2][2], L[2][3]);
  d1[2] = packrne(L[3][0], L[3][1]); d1[3] = packrne(L[3][2], L[3][3]);
  *(uint4v*)&buf[r0 * KSTR + c * 8]        = d0;
  *(uint4v*)&buf[(r0 + 32) * KSTR + c * 8] = d1;
}

// stage V^T tile image (256 threads): chunk a=tS>>4 of vcol=4x+j (x=tS&15)
// at slot (a+x)&15 on 136B rows.
DEV void stageV(unsigned short* buf, const f32x4* L, int tS) {
  const int a = tS >> 4;
  const int x = tS & 15;
  const int slot = (a + x) & 15;
#pragma unroll
  for (int j = 0; j < 4; ++j) {
    uint2v d;
    d[0] = packrne(L[0][j], L[1][j]);
    d[1] = packrne(L[2][j], L[3][j]);
    *(uint2v*)&buf[(x * 4 + j) * VSTR + slot * 4] = d;
  }
}

// async 16B global->LDS DMA
DEV void dma16(const void* g, void* l) {
#if __has_builtin(__builtin_amdgcn_global_load_lds)
  __builtin_amdgcn_global_load_lds(
      (const __attribute__((address_space(1))) unsigned int*)g,
      (__attribute__((address_space(3))) unsigned int*)l, 16, 0, 0);
#else
  ((uint4v*)l)[threadIdx.x & 63] = *(const uint4v*)g;
#endif
}

// 8-wave tile DMA (512-thr kernel)
DEV void dmaTile(const char* gt, void* lk, void* lv, int w, int laneB) {
  if (w < 4) {
    const int base = w * 2048;
    dma16(gt + base + laneB,        (char*)lk + base);
    dma16(gt + base + 1024 + laneB, (char*)lk + base + 1024);
    if (w == 0) dma16(gt + 8192 + laneB, (char*)lk + 8192);
  } else {
    const char* g = gt + KIMG_B;
    const int base = (w - 4) * 2048;
    dma16(g + base + laneB,        (char*)lv + base);
    dma16(g + base + 1024 + laneB, (char*)lv + base + 1024);
    if (w == 4) dma16(g + 8192 + laneB, (char*)lv + 8192);
  }
}

// 4-wave tile DMA (256-thr dual kernel): 18 x 1KB chunks round-robin.
DEV void dmaTile4(const char* gt, char* lk, char* lv, int w, int laneB) {
#pragma unroll
  for (int i = 0; i < 5; ++i) {
    const int c = w + 4 * i;           // wave-uniform
    if (c < 18) {
      if (c < 9) dma16(gt + c * 1024 + laneB, lk + c * 1024);
      else dma16(gt + KIMG_B + (c - 9) * 1024 + laneB, lv + (c - 9) * 1024);
    }
  }
}

// ---- prep: build per-(n,tile) bf16 LDS images in workspace
__global__ __launch_bounds__(256)
void sdpa_prep(const float* __restrict__ Kg, const float* __restrict__ Vg,
               unsigned short* __restrict__ imgs) {
  const int b   = blockIdx.x;           // n*64 + tau
  const int n   = b >> 6, tau = b & 63;
  const int tS  = threadIdx.x;
  unsigned short* img = imgs + (size_t)b * (TILE_B / 2);
  {
    const float* kp =
        Kg + ((size_t)n * S_KV + tau * 64 + (tS >> 3)) * DH + (tS & 7) * 8;
    f32x4 L[4];
    L[0] = *(const f32x4*)(kp);
    L[1] = *(const f32x4*)(kp + 4);
    L[2] = *(const f32x4*)(kp + 32 * DH);
    L[3] = *(const f32x4*)(kp + 32 * DH + 4);
    stageK(img, L, tS);
  }
  {
    const float* vp =
        Vg + ((size_t)n * S_KV + tau * 64 + (size_t)(tS >> 4) * 4) * DH
           + (tS & 15) * 4;
    f32x4 L[4];
#pragma unroll
    for (int i = 0; i < 4; ++i) L[i] = *(const f32x4*)(vp + i * DH);
    stageV(img + KIMG_B / 2, L, tS);
  }
}

// ---- v15 primary: dual-stream 4-wave DMA kernel, atomic KV-split combine
template <int MW>
__global__ __launch_bounds__(256, MW)
void sdpa_fwd_dual(const float* __restrict__ Qg,
                   const float* __restrict__ Mg,
                   const unsigned short* __restrict__ imgs,
                   float* __restrict__ Og,      // zero-initialized
                   float* __restrict__ Lbuf,    // zero-initialized [n][q]
                   int nIter)
{
  __shared__ __align__(16) unsigned short ldsK[2][KIMG_B / 2];
  __shared__ __align__(16) unsigned short ldsV[2][VIMG_B / 2];

  const int n     = blockIdx.y;
  const int q0    = blockIdx.x * BQ;
  const int z     = blockIdx.z;
  const int t     = threadIdx.x;
  const int w     = t >> 6;                    // wave 0..3
  const int lane  = t & 63;
  const int l15   = lane & 15;
  const int quad  = lane >> 4;
  const int qA    = q0 + w * 32 + l15;         // stream A q; B = qA+16
  const int laneB = lane * 16;
  const int tbase = n * 64 + z * nIter;

  // Q B-frags for two 16-q streams, pre-scaled by 0.125*log2e
  short8 qfA0, qfA1, qfB0, qfB1;
  {
    const float* qp = Qg + ((size_t)n * S_Q + (size_t)qA) * DH + quad * 8;
#pragma unroll
    for (int j = 0; j < 8; ++j) {
      qfA0[j] = (short)f2bf(qp[j] * QSCALE);
      qfA1[j] = (short)f2bf(qp[32 + j] * QSCALE);
      qfB0[j] = (short)f2bf(qp[16 * DH + j] * QSCALE);
      qfB1[j] = (short)f2bf(qp[16 * DH + 32 + j] * QSCALE);
    }
  }

  const float* mrowA =
      Mg + (size_t)qA * S_KV + (size_t)z * nIter * BK + quad * 4;
  const float* mrowB = mrowA + (size_t)16 * S_KV;

  f32x4 accA[4], accB[4];
#pragma unroll
  for (int nt = 0; nt < 4; ++nt)
#pragma unroll
    for (int r = 0; r < 4; ++r) { accA[nt][r] = 0.0f; accB[nt][r] = 0.0f; }
  float rsA = 0.0f, rsB = 0.0f;

  dmaTile4((const char*)imgs + (size_t)tbase * TILE_B,
           (char*)&ldsK[0][0], (char*)&ldsV[0][0], w, laneB);
  __syncthreads();

  for (int it = 0; it < nIter; ++it) {
    const int p   = it & 1;
    const int kv0 = it * BK;
    const bool more = (it + 1 < nIter);

    if (more)
      dmaTile4((const char*)imgs + (size_t)(tbase + it + 1) * TILE_B,
               (char*)&ldsK[p ^ 1][0], (char*)&ldsV[p ^ 1][0], w, laneB);

    // phase 1: per-h { kf read (shared by streams), mask, QK, exp, rs, pack }
    short4v pfA[4], pfB[4];
#pragma unroll
    for (int h = 0; h < 4; ++h) {
      const short8 kf0 =
          *(const short8*)&ldsK[p][(l15 + 16 * h) * KSTR + quad * 8];
      const short8 kf1 =
          *(const short8*)&ldsK[p][(l15 + 16 * h) * KSTR + (quad + 4) * 8];
      const f32x4 mkA = *(const f32x4*)(mrowA + kv0 + 16 * h);
      const f32x4 mkB = *(const f32x4*)(mrowB + kv0 + 16 * h);
      f32x4 cA = {0.f, 0.f, 0.f, 0.f}, cB = {0.f, 0.f, 0.f, 0.f};
      __builtin_amdgcn_s_setprio(1);
      cA = __builtin_amdgcn_mfma_f32_16x16x32_bf16(kf0, qfA0, cA, 0, 0, 0);
      cB = __builtin_amdgcn_mfma_f32_16x16x32_bf16(kf0, qfB0, cB, 0, 0, 0);
      cA = __builtin_amdgcn_mfma_f32_16x16x32_bf16(kf1, qfA1, cA, 0, 0, 0);
      cB = __builtin_amdgcn_mfma_f32_16x16x32_bf16(kf1, qfB1, cB, 0, 0, 0);
      __builtin_amdgcn_s_setprio(0);
      float eA[4], eB[4];
#pragma unroll
      for (int r = 0; r < 4; ++r) {
        eA[r] = __builtin_amdgcn_exp2f(fmaf(mkA[r], LOG2E, cA[r]));
        eB[r] = __builtin_amdgcn_exp2f(fmaf(mkB[r], LOG2E, cB[r]));
      }
      rsA += (eA[0] + eA[1]) + (eA[2] + eA[3]);
      rsB += (eB[0] + eB[1]) + (eB[2] + eB[3]);
      union { uint2v u; short4v s; } ua, ub;
      ua.u[0] = packrne(eA[0], eA[1]); ua.u[1] = packrne(eA[2], eA[3]);
      ub.u[0] = packrne(eB[0], eB[1]); ub.u[1] = packrne(eB[2], eB[3]);
      pfA[h] = ua.s; pfB[h] = ub.s;
    }

    // PV: each vf read feeds BOTH streams
    __builtin_amdgcn_s_setprio(1);
#pragma unroll
    for (int nt = 0; nt < 4; ++nt) {
      const int vcol = l15 + 16 * nt;
      const int xr   = (l15 >> 2) + 4 * nt;
#pragma unroll
      for (int h = 0; h < 4; ++h) {
        const int slot = ((4 * h + quad) + xr) & 15;
        short4v vf = *(const short4v*)&ldsV[p][vcol * VSTR + slot * 4];
        accA[nt] = mfma16(vf, pfA[h], accA[nt]);
        accB[nt] = mfma16(vf, pfB[h], accB[nt]);
      }
    }
    __builtin_amdgcn_s_setprio(0);

    __syncthreads();
  }

  // epilogue: cross-quad reduce once; atomic combine into O / L
  rsA += __shfl_xor(rsA, 16, 64);
  rsA += __shfl_xor(rsA, 32, 64);
  rsB += __shfl_xor(rsB, 16, 64);
  rsB += __shfl_xor(rsB, 32, 64);
  if (quad == 0) {
    atomicAdd(&Lbuf[(size_t)n * S_Q + qA],      rsA);
    atomicAdd(&Lbuf[(size_t)n * S_Q + qA + 16], rsB);
  }
  float* obA = Og + ((size_t)n * S_Q + (size_t)qA) * DH + quad * 4;
  float* obB = obA + (size_t)16 * DH;
#pragma unroll
  for (int nt = 0; nt < 4; ++nt)
#pragma unroll
    for (int r = 0; r < 4; ++r) {
      atomicAdd(obA + 16 * nt + r, accA[nt][r]);
      atomicAdd(obB + 16 * nt + r, accB[nt][r]);
    }
}

// zero O and Lbuf
__global__ __launch_bounds__(256)
void sdpa_zero(float* __restrict__ Og, float* __restrict__ Lbuf) {
  constexpr size_t NS = (size_t)N_B * S_Q;
  const size_t i = (size_t)blockIdx.x * 256 + threadIdx.x;
  const f32x4 zz = {0.f, 0.f, 0.f, 0.f};
  ((f32x4*)Og)[i] = zz;
  if (i < NS / 4) ((f32x4*)Lbuf)[i] = zz;
}

// normalize: O[i] /= L[row]
__global__ __launch_bounds__(256)
void sdpa_norm(float* __restrict__ Og, const float* __restrict__ Lbuf) {
  const size_t i = (size_t)blockIdx.x * 256 + threadIdx.x;  // f32x4 index
  const size_t qi = i >> 4;                                 // 16 f32x4 per row
  f32x4 v = ((f32x4*)Og)[i];
  const float inv = 1.0f / Lbuf[qi];
#pragma unroll
  for (int r = 0; r < 4; ++r) v[r] *= inv;
  ((f32x4*)Og)[i] = v;
}

// ---- r9-proven fallback: 512-thr single-stream DMA kernel (single pass)
template <int MW>
__global__ __launch_bounds__(512, MW)
void sdpa_fwd_dma(const float* __restrict__ Qg,
                  const float* __restrict__ Mg,
                  const unsigned short* __restrict__ imgs,
                  float* __restrict__ Og, int nIter)
{
  __shared__ __align__(16) unsigned short ldsK[2][KIMG_B / 2];
  __shared__ __align__(16) unsigned short ldsV[2][VIMG_B / 2];

  const int n     = blockIdx.y;
  const int q0    = blockIdx.x * BQ;
  const int t     = threadIdx.x;
  const int w     = t >> 6;
  const int lane  = t & 63;
  const int l15   = lane & 15;
  const int quad  = lane >> 4;
  const int qrow  = q0 + w * 16 + l15;
  const int laneB = lane * 16;
  const int tbase = n * 64;

  short8 qf0, qf1;
  {
    const float* qp = Qg + ((size_t)n * S_Q + (size_t)qrow) * DH + quad * 8;
#pragma unroll
    for (int j = 0; j < 8; ++j) {
      qf0[j] = (short)f2bf(qp[j] * QSCALE);
      qf1[j] = (short)f2bf(qp[32 + j] * QSCALE);
    }
  }
  const float* mrow = Mg + (size_t)qrow * S_KV + quad * 4;

  f32x4 acc[4];
#pragma unroll
  for (int nt = 0; nt < 4; ++nt)
#pragma unroll
    for (int r = 0; r < 4; ++r) acc[nt][r] = 0.0f;
  float rs = 0.0f;

  dmaTile((const char*)imgs + (size_t)tbase * TILE_B,
          &ldsK[0][0], &ldsV[0][0], w, laneB);
  __syncthreads();

  for (int it = 0; it < nIter; ++it) {
    const int p   = it & 1;
    const int kv0 = it * BK;
    const bool more = (it + 1 < nIter);

    if (more)
      dmaTile((const char*)imgs + (size_t)(tbase + it + 1) * TILE_B,
              &ldsK[p ^ 1][0], &ldsV[p ^ 1][0], w, laneB);

    short4v pf[4];
#pragma unroll
    for (int h = 0; h < 4; ++h) {
      const short8 kf0 =
          *(const short8*)&ldsK[p][(l15 + 16 * h) * KSTR + quad * 8];
      const short8 kf1 =
          *(const short8*)&ldsK[p][(l15 + 16 * h) * KSTR + (quad + 4) * 8];
      const f32x4 mk = *(const f32x4*)(mrow + kv0 + 16 * h);
      f32x4 c = {0.f, 0.f, 0.f, 0.f};
      __builtin_amdgcn_s_setprio(1);
      c = __builtin_amdgcn_mfma_f32_16x16x32_bf16(kf0, qf0, c, 0, 0, 0);
      c = __builtin_amdgcn_mfma_f32_16x16x32_bf16(kf1, qf1, c, 0, 0, 0);
      __builtin_amdgcn_s_setprio(0);
      float e[4];
#pragma unroll
      for (int r = 0; r < 4; ++r)
        e[r] = __builtin_amdgcn_exp2f(fmaf(mk[r], LOG2E, c[r]));
      rs += (e[0] + e[1]) + (e[2] + e[3]);
      union { uint2v u; short4v s; } ue;
      ue.u[0] = packrne(e[0], e[1]);
      ue.u[1] = packrne(e[2], e[3]);
      pf[h] = ue.s;
    }

    __builtin_amdgcn_s_setprio(1);
#pragma unroll
    for (int nt = 0; nt < 4; ++nt) {
      const int vcol = l15 + 16 * nt;
      const int xr   = (l15 >> 2) + 4 * nt;
#pragma unroll
      for (int h = 0; h < 4; ++h) {
        const int slot = ((4 * h + quad) + xr) & 15;
        short4v vf = *(const short4v*)&ldsV[p][vcol * VSTR + slot * 4];
        acc[nt] = mfma16(vf, pf[h], acc[nt]);
      }
    }
    __builtin_amdgcn_s_setprio(0);

    __syncthreads();
  }

  rs += __shfl_xor(rs, 16, 64);
  rs += __shfl_xor(rs, 32, 64);
  const float inv = 1.0f / rs;
  float* ob = Og + ((size_t)n * S_Q + (size_t)qrow) * DH + quad * 4;
#pragma unroll
  for (int nt = 0; nt < 4; ++nt) {
    f32x4 o;
#pragma unroll
    for (int r = 0; r < 4; ++r) o[r] = acc[nt][r] * inv;
    *(f32x4*)(ob + 16 * nt) = o;
  }
}

// ---- ultimate fallback: r8-proven reg-staging single-pass
__global__ __launch_bounds__(512, 4)
void sdpa_fwd_reg(const float* __restrict__ Qg, const float* __restrict__ Kg,
                  const float* __restrict__ Vg, const float* __restrict__ Mg,
                  float* __restrict__ Og)
{
  __shared__ __align__(16) unsigned short ldsK[2][BK * KSTR];
  __shared__ __align__(16) unsigned short ldsV[2][DH * VSTR];

  const int n = blockIdx.y, q0 = blockIdx.x * BQ, t = threadIdx.x;
  const int w = t >> 6, lane = t & 63, l15 = lane & 15, quad = lane >> 4;
  const int qrow = q0 + w * 16 + l15;

  short8 qf0, qf1;
  {
    const float* qp = Qg + ((size_t)n * S_Q + (size_t)qrow) * DH + quad * 8;
#pragma unroll
    for (int j = 0; j < 8; ++j) {
      qf0[j] = (short)f2bf(qp[j] * QSCALE);
      qf1[j] = (short)f2bf(qp[32 + j] * QSCALE);
    }
  }
  const bool isK = (w < 4);
  const int  tS  = t & 255;
  const float* sgp =
      isK ? Kg + ((size_t)n * S_KV + (size_t)(tS >> 3)) * DH + (tS & 7) * 8
          : Vg + ((size_t)n * S_KV + (size_t)(tS >> 4) * 4) * DH + (tS & 15) * 4;
  const float* mrow = Mg + (size_t)qrow * S_KV + quad * 4;

  f32x4 acc[4];
#pragma unroll
  for (int nt = 0; nt < 4; ++nt)
#pragma unroll
    for (int r = 0; r < 4; ++r) acc[nt][r] = 0.0f;
  float rs = 0.0f;

  {
    f32x4 L[4];
    if (isK) {
      L[0] = *(const f32x4*)(sgp);
      L[1] = *(const f32x4*)(sgp + 4);
      L[2] = *(const f32x4*)(sgp + 32 * DH);
      L[3] = *(const f32x4*)(sgp + 32 * DH + 4);
      stageK(&ldsK[0][0], L, tS);
    } else {
#pragma unroll
      for (int i = 0; i < 4; ++i) L[i] = *(const f32x4*)(sgp + i * DH);
      stageV(&ldsV[0][0], L, tS);
    }
  }
  __syncthreads();

  for (int it = 0; it < ITERS; ++it) {
    const int p = it & 1, kv0 = it * BK;
    const bool more = (it + 1 < ITERS);
    short4v pf[4];
#pragma unroll
    for (int h = 0; h < 4; ++h) {
      const short8 kf0 =
          *(const short8*)&ldsK[p][(l15 + 16 * h) * KSTR + quad * 8];
      const short8 kf1 =
          *(const short8*)&ldsK[p][(l15 + 16 * h) * KSTR + (quad + 4) * 8];
      const f32x4 mk = *(const f32x4*)(mrow + kv0 + 16 * h);
      f32x4 c = {0.f, 0.f, 0.f, 0.f};
      c = __builtin_amdgcn_mfma_f32_16x16x32_bf16(kf0, qf0, c, 0, 0, 0);
      c = __builtin_amdgcn_mfma_f32_16x16x32_bf16(kf1, qf1, c, 0, 0, 0);
      float e[4];
#pragma unroll
      for (int r = 0; r < 4; ++r)
        e[r] = __builtin_amdgcn_exp2f(fmaf(mk[r], LOG2E, c[r]));
      rs += (e[0] + e[1]) + (e[2] + e[3]);
      union { uint2v u; short4v s; } ue;
      ue.u[0] = packrne(e[0], e[1]);
      ue.u[1] = packrne(e[2], e[3]);
      pf[h] = ue.s;
    }
    f32x4 L[4];
    if (more) {
      const float* np = sgp + (size_t)(kv0 + BK) * DH;
      if (isK) {
        L[0] = *(const f32x4*)(np);
        L[1] = *(const f32x4*)(np + 4);
        L[2] = *(const f32x4*)(np + 32 * DH);
        L[3] = *(const f32x4*)(np + 32 * DH + 4);
      } else {
#pragma unroll
        for (int i = 0; i < 4; ++i) L[i] = *(const f32x4*)(np + i * DH);
      }
    }
#pragma unroll
    for (int nt = 0; nt < 4; ++nt) {
      const int vcol = l15 + 16 * nt;
      const int xr   = (l15 >> 2) + 4 * nt;
#pragma unroll
      for (int h = 0; h < 4; ++h) {
        const int slot = ((4 * h + quad) + xr) & 15;
        short4v vf = *(const short4v*)&ldsV[p][vcol * VSTR + slot * 4];
        acc[nt] = mfma16(vf, pf[h], acc[nt]);
      }
    }
    if (more) {
      if (isK) stageK(&ldsK[p ^ 1][0], L, tS);
      else     stageV(&ldsV[p ^ 1][0], L, tS);
    }
    __syncthreads();
  }

  rs += __shfl_xor(rs, 16, 64);
  rs += __shfl_xor(rs, 32, 64);
  const float inv = 1.0f / rs;
  float* ob = Og + ((size_t)n * S_Q + (size_t)qrow) * DH + quad * 4;
#pragma unroll
  for (int nt = 0; nt < 4; ++nt) {
    f32x4 o;
#pragma unroll
    for (int r = 0; r < 4; ++r) o[r] = acc[nt][r] * inv;
    *(f32x4*)(ob + 16 * nt) = o;
  }
}

extern "C" void kernel_launch(void* const* d_in, const int* in_sizes, int n_in,
                              void* d_out, int out_size, void* d_ws, size_t ws_size,
                              hipStream_t stream) {
  (void)in_sizes; (void)n_in; (void)out_size;
  const float* q = (const float*)d_in[0];
  const float* k = (const float*)d_in[1];
  const float* v = (const float*)d_in[2];
  const float* m = (const float*)d_in[3];
  float* o = (float*)d_out;

  constexpr size_t NSV = (size_t)N_B * S_Q * DH;
  constexpr size_t NS  = (size_t)N_B * S_Q;
  constexpr size_t IMG_BYTES = (size_t)N_B * 64 * TILE_B;          // 18.87 MB
  constexpr size_t DUAL_NEED = IMG_BYTES + NS * sizeof(float);     // 19.14 MB

  // spill tripwire on the dual build (r8-proven pattern)
  static int useDual = -1;
  if (useDual < 0) {
    hipFuncAttributes attr{};
    useDual = 0;
    if (hipFuncGetAttributes(&attr,
            reinterpret_cast<const void*>(&sdpa_fwd_dual<4>)) == hipSuccess &&
        attr.localSizeBytes == 0)
      useDual = 1;
  }

  if (d_ws != nullptr && ws_size >= DUAL_NEED && useDual) {
    // Path A: dual-stream + atomic KV-split -> 4 blocks/CU, 4 barrier groups
    unsigned short* imgs = (unsigned short*)d_ws;
    float* lbuf = (float*)((char*)d_ws + IMG_BYTES);
    hipLaunchKernelGGL(sdpa_prep, dim3(N_B * 64), dim3(256), 0, stream,
                       k, v, imgs);
    hipLaunchKernelGGL(sdpa_zero, dim3((unsigned)(NSV / 4 / 256)), dim3(256),
                       0, stream, o, lbuf);
    dim3 grid(S_Q / BQ, N_B, 2);   // 1024 blocks x 256 thr
    hipLaunchKernelGGL((sdpa_fwd_dual<4>), grid, dim3(256), 0, stream,
                       q, m, imgs, o, lbuf, ITERS / 2);
    hipLaunchKernelGGL(sdpa_norm, dim3((unsigned)(NSV / 4 / 256)), dim3(256),
                       0, stream, o, (const float*)lbuf);
  } else if (d_ws != nullptr && ws_size >= IMG_BYTES) {
    // Path B: r9-proven single-pass DMA (512-thr)
    unsigned short* imgs = (unsigned short*)d_ws;
    hipLaunchKernelGGL(sdpa_prep, dim3(N_B * 64), dim3(256), 0, stream,
                       k, v, imgs);
    dim3 grid(S_Q / BQ, N_B, 1);
    hipLaunchKernelGGL((sdpa_fwd_dma<4>), grid, dim3(512), 0, stream,
                       q, m, imgs, o, ITERS);
  } else {
    // Path C: r8-proven reg-staging single-pass
    dim3 grid(S_Q / BQ, N_B);
    hipLaunchKernelGGL(sdpa_fwd_reg, grid, dim3(512), 0, stream,
                       q, k, v, m, o);
  }
}

// Round 11
// 288.432 us; speedup vs baseline: 1.0283x; 1.0283x over previous
//
#include <hip/hip_runtime.h>
#include <cstdint>
#include <cstddef>

// ---------------------------------------------------------------------------
// NaiveSDPA: out[n,s,v] = softmax(Q·K^T / 8 + mask) · V ; f32 I/O, bf16 MFMA.
// v16: attach the KV-split to the kernel that FITS, and kill the kf conflict.
// r10 ledger: the proven single-stream DMA kernel runs at VGPR=36 arch
// (~54 combined <= 64 tier) but its grid (512 blocks) caps it at 2 blocks/CU
// (45% occ). The dual kernel (r10's split carrier) spills and is abandoned.
// v16:
//   - KV-split x2 on sdpa_fwd_dma itself: grid (32,16,2) = 1024 x 512thr =
//     4 blocks/CU = 32 waves/CU (LDS 4x34.8KB=139KB<=160, thr 2048 = max).
//     launch_bounds(512,8): honest fit (54 < 64), r8-proven spill tripwire.
//     Combine: Path A = partials + combine pass (ws>=52MB, r2-proven math);
//     Path A2 = zero-init + f32 atomicAdd + norm (ws>=18.1MB).
//   - K image: 128B rows + XOR chunk swizzle (chunk ^= row&7). Old 144B-skew
//     rows gave bank start 4*(l15+quad)%32 = 8 starts/phase = 4-WAY conflict
//     (~600 of 672 conflict-cy/block-iter). New: 2-way (free, m136). Swizzle
//     applied on BOTH sides (prep write + kf read); DMA is a byte copy.
//     K image 9216->8192B, TILE_B 17408.
// Fallbacks: Path B single-pass DMA (r10 behavior + swizzle), Path C
// reg-staging (updated to the same K layout).
// ---------------------------------------------------------------------------

typedef __attribute__((ext_vector_type(8))) short short8;
typedef __attribute__((ext_vector_type(4))) short short4v;
typedef __attribute__((ext_vector_type(4))) float f32x4;
typedef __attribute__((ext_vector_type(4))) unsigned int uint4v;
typedef __attribute__((ext_vector_type(2))) unsigned int uint2v;

#define DEV __device__ __forceinline__

constexpr int N_B   = 16;
constexpr int S_Q   = 4096;
constexpr int S_KV  = 4096;
constexpr int DH    = 64;
constexpr int BQ    = 128;         // q rows per block (8 waves x 16)
constexpr int BK    = 64;
constexpr int ITERS = S_KV / BK;   // 64 tiles
constexpr int KROW  = 64;          // shorts/K-row: 128B, XOR-swizzled chunks
constexpr int VSTR  = 68;          // shorts/V^T-row: 136B (16 slots + pad)
constexpr int KIMG_B = 8192;       // K tile image bytes (64 x 128B)
constexpr int VIMG_B = 9216;       // V tile image bytes (8704 + 512 pad)
constexpr int TILE_B = KIMG_B + VIMG_B;   // 17408

#define LOG2E 1.44269504088896340736f
#define QSCALE (0.125f * 1.44269504088896340736f)   // fold /8 + log2e into Q

DEV unsigned short f2bf(float f) {           // RNE f32 -> bf16
  union { float f; unsigned int i; } x; x.f = f;
  unsigned int r = x.i + 0x7FFFu + ((x.i >> 16) & 1u);
  return (unsigned short)(r >> 16);
}

#if __has_builtin(__builtin_amdgcn_cvt_pk_bf16_f32)
typedef __attribute__((ext_vector_type(2))) __bf16 bf16x2v;
DEV unsigned int packrne(float a, float b) {   // bf16(a) lo | bf16(b) hi, RNE
  union { bf16x2v v; unsigned int u; } x;
  x.v = __builtin_amdgcn_cvt_pk_bf16_f32(a, b);
  return x.u;
}
#else
DEV unsigned int packrne(float a, float b) {
  union { float f; unsigned int u; } ua, ub; ua.f = a; ub.f = b;
  unsigned int ra = ua.u + 0x7FFFu + ((ua.u >> 16) & 1u);
  unsigned int rb = ub.u + 0x7FFFu + ((ub.u >> 16) & 1u);
  return __builtin_amdgcn_perm(rb, ra, 0x07060302u);
}
#endif

DEV f32x4 mfma16(short4v a, short4v b, f32x4 c) {
#if __has_builtin(__builtin_amdgcn_mfma_f32_16x16x16bf16_1k)
  return __builtin_amdgcn_mfma_f32_16x16x16bf16_1k(a, b, c, 0, 0, 0);
#elif __has_builtin(__builtin_amdgcn_mfma_f32_16x16x16_bf16)
  return __builtin_amdgcn_mfma_f32_16x16x16_bf16(a, b, c, 0, 0, 0);
#else
  asm volatile("v_mfma_f32_16x16x16_bf16 %0, %1, %2, %0\n\ts_nop 7\n\ts_nop 7"
               : "+v"(c) : "v"(a), "v"(b));
  return c;
#endif
}

// stage K tile image (256 threads): thread tS owns rows r0=tS>>3 and r0+32,
// chunk c=tS&7. NEW layout: 128B rows, chunk stored at (c ^ (row&7))*16B.
// (r0+32)&7 == r0&7, so one swizzled chunk index serves both rows.
DEV void stageK(unsigned short* buf, const f32x4* L, int tS) {
  const int r0 = tS >> 3, c = tS & 7;
  const int cs = (c ^ (r0 & 7)) * 8;          // shorts
  uint4v d0, d1;
  d0[0] = packrne(L[0][0], L[0][1]); d0[1] = packrne(L[0][2], L[0][3]);
  d0[2] = packrne(L[1][0], L[1][1]); d0[3] = packrne(L[1][2], L[1][3]);
  d1[0] = packrne(L[2][0], L[2][1]); d1[1] = packrne(L[2][2], L[2][3]);
  d1[2] = packrne(L[3][0], L[3][1]); d1[3] = packrne(L[3][2], L[3][3]);
  *(uint4v*)&buf[r0 * KROW + cs]        = d0;
  *(uint4v*)&buf[(r0 + 32) * KROW + cs] = d1;
}

// stage V^T tile image (256 threads): chunk a=tS>>4 of vcol=4x+j (x=tS&15)
// at slot (a+x)&15 on 136B rows (unchanged, conflict-verified pattern).
DEV void stageV(unsigned short* buf, const f32x4* L, int tS) {
  const int a = tS >> 4;
  const int x = tS & 15;
  const int slot = (a + x) & 15;
#pragma unroll
  for (int j = 0; j < 4; ++j) {
    uint2v d;
    d[0] = packrne(L[0][j], L[1][j]);
    d[1] = packrne(L[2][j], L[3][j]);
    *(uint2v*)&buf[(x * 4 + j) * VSTR + slot * 4] = d;
  }
}

// async 16B global->LDS DMA
DEV void dma16(const void* g, void* l) {
#if __has_builtin(__builtin_amdgcn_global_load_lds)
  __builtin_amdgcn_global_load_lds(
      (const __attribute__((address_space(1))) unsigned int*)g,
      (__attribute__((address_space(3))) unsigned int*)l, 16, 0, 0);
#else
  ((uint4v*)l)[threadIdx.x & 63] = *(const uint4v*)g;
#endif
}

// 8-wave tile DMA: K image 8KB (waves 0-3 x2), V image 9KB (waves 4-7 x2 +
// wave4 x1). All LDS bases wave-uniform + lane*16 (HW requirement).
DEV void dmaTile(const char* gt, void* lk, void* lv, int w, int laneB) {
  if (w < 4) {
    const int base = w * 2048;
    dma16(gt + base + laneB,        (char*)lk + base);
    dma16(gt + base + 1024 + laneB, (char*)lk + base + 1024);
  } else {
    const char* g = gt + KIMG_B;
    const int base = (w - 4) * 2048;
    dma16(g + base + laneB,        (char*)lv + base);
    dma16(g + base + 1024 + laneB, (char*)lv + base + 1024);
    if (w == 4) dma16(g + 8192 + laneB, (char*)lv + 8192);
  }
}

// ---- prep: build per-(n,tile) bf16 LDS images in workspace (~13us)
__global__ __launch_bounds__(256)
void sdpa_prep(const float* __restrict__ Kg, const float* __restrict__ Vg,
               unsigned short* __restrict__ imgs) {
  const int b   = blockIdx.x;           // n*64 + tau
  const int n   = b >> 6, tau = b & 63;
  const int tS  = threadIdx.x;
  unsigned short* img = imgs + (size_t)b * (TILE_B / 2);
  {
    const float* kp =
        Kg + ((size_t)n * S_KV + tau * 64 + (tS >> 3)) * DH + (tS & 7) * 8;
    f32x4 L[4];
    L[0] = *(const f32x4*)(kp);
    L[1] = *(const f32x4*)(kp + 4);
    L[2] = *(const f32x4*)(kp + 32 * DH);
    L[3] = *(const f32x4*)(kp + 32 * DH + 4);
    stageK(img, L, tS);
  }
  {
    const float* vp =
        Vg + ((size_t)n * S_KV + tau * 64 + (size_t)(tS >> 4) * 4) * DH
           + (tS & 15) * 4;
    f32x4 L[4];
#pragma unroll
    for (int i = 0; i < 4; ++i) L[i] = *(const f32x4*)(vp + i * DH);
    stageV(img + KIMG_B / 2, L, tS);
  }
}

// ---- main: DMA-staged attention; mode 0 = finalize, 1 = ws partials,
// 2 = atomicAdd into zero-initialized O/L.
template <int MW>
__global__ __launch_bounds__(512, MW)
void sdpa_fwd_dma(const float* __restrict__ Qg,
                  const float* __restrict__ Mg,
                  const unsigned short* __restrict__ imgs,
                  float* __restrict__ Ob,
                  float* __restrict__ Lb,
                  int nIter, int mode)
{
  __shared__ __align__(16) unsigned short ldsK[2][KIMG_B / 2];  // 2 x 8192 B
  __shared__ __align__(16) unsigned short ldsV[2][VIMG_B / 2];  // 2 x 9216 B

  const int n     = blockIdx.y;
  const int q0    = blockIdx.x * BQ;
  const int z     = blockIdx.z;
  const int t     = threadIdx.x;
  const int w     = t >> 6;
  const int lane  = t & 63;
  const int l15   = lane & 15;
  const int quad  = lane >> 4;
  const int qrow  = q0 + w * 16 + l15;
  const int laneB = lane * 16;
  const int tbase = n * 64 + z * nIter;

  // Q B-frags, pre-scaled by 0.125*log2e (softmax scale-invariant)
  short8 qf0, qf1;
  {
    const float* qp = Qg + ((size_t)n * S_Q + (size_t)qrow) * DH + quad * 8;
#pragma unroll
    for (int j = 0; j < 8; ++j) {
      qf0[j] = (short)f2bf(qp[j] * QSCALE);
      qf1[j] = (short)f2bf(qp[32 + j] * QSCALE);
    }
  }

  const float* mrow =
      Mg + (size_t)qrow * S_KV + (size_t)z * nIter * BK + quad * 4;

  // swizzled kf chunk offsets (shorts), hoisted: chunk = (quad|quad+4)^swz
  const int swz = l15 & 7;
  const int c0 = (quad ^ swz) * 8;
  const int c1 = ((quad + 4) ^ swz) * 8;

  f32x4 acc[4];
#pragma unroll
  for (int nt = 0; nt < 4; ++nt)
#pragma unroll
    for (int r = 0; r < 4; ++r) acc[nt][r] = 0.0f;
  float rs = 0.0f;

  dmaTile((const char*)imgs + (size_t)tbase * TILE_B,
          &ldsK[0][0], &ldsV[0][0], w, laneB);
  __syncthreads();

  for (int it = 0; it < nIter; ++it) {
    const int p   = it & 1;
    const int kv0 = it * BK;
    const bool more = (it + 1 < nIter);

    if (more)
      dmaTile((const char*)imgs + (size_t)(tbase + it + 1) * TILE_B,
              &ldsK[p ^ 1][0], &ldsV[p ^ 1][0], w, laneB);

    const unsigned short* kb = &ldsK[p][l15 * KROW];

    short4v pf[4];
#pragma unroll
    for (int h = 0; h < 4; ++h) {
      // row l15+16h -> kb + h*1024 shorts; swizzled chunks c0/c1
      const short8 kf0 = *(const short8*)(kb + h * 1024 + c0);
      const short8 kf1 = *(const short8*)(kb + h * 1024 + c1);
      const f32x4 mk = *(const f32x4*)(mrow + kv0 + 16 * h);
      f32x4 c = {0.f, 0.f, 0.f, 0.f};
      __builtin_amdgcn_s_setprio(1);
      c = __builtin_amdgcn_mfma_f32_16x16x32_bf16(kf0, qf0, c, 0, 0, 0);
      c = __builtin_amdgcn_mfma_f32_16x16x32_bf16(kf1, qf1, c, 0, 0, 0);
      __builtin_amdgcn_s_setprio(0);
      float e[4];
#pragma unroll
      for (int r = 0; r < 4; ++r)
        e[r] = __builtin_amdgcn_exp2f(fmaf(mk[r], LOG2E, c[r]));
      rs += (e[0] + e[1]) + (e[2] + e[3]);
      union { uint2v u; short4v s; } ue;
      ue.u[0] = packrne(e[0], e[1]);
      ue.u[1] = packrne(e[2], e[3]);
      pf[h] = ue.s;
    }

    // PV: O^T += V^T·P^T
    __builtin_amdgcn_s_setprio(1);
#pragma unroll
    for (int nt = 0; nt < 4; ++nt) {
      const int vcol = l15 + 16 * nt;
      const int xr   = (l15 >> 2) + 4 * nt;
#pragma unroll
      for (int h = 0; h < 4; ++h) {
        const int slot = ((4 * h + quad) + xr) & 15;
        short4v vf = *(const short4v*)&ldsV[p][vcol * VSTR + slot * 4];
        acc[nt] = mfma16(vf, pf[h], acc[nt]);
      }
    }
    __builtin_amdgcn_s_setprio(0);

    __syncthreads();   // drains DMA + orders buffer reuse
  }

  rs += __shfl_xor(rs, 16, 64);
  rs += __shfl_xor(rs, 32, 64);

  if (mode == 0) {
    const float inv = 1.0f / rs;
    float* ob = Ob + ((size_t)n * S_Q + (size_t)qrow) * DH + quad * 4;
#pragma unroll
    for (int nt = 0; nt < 4; ++nt) {
      f32x4 o;
#pragma unroll
      for (int r = 0; r < 4; ++r) o[r] = acc[nt][r] * inv;
      *(f32x4*)(ob + 16 * nt) = o;
    }
  } else if (mode == 1) {
    const size_t NSV = (size_t)N_B * S_Q * DH;
    float* ob = Ob + (size_t)z * NSV + ((size_t)n * S_Q + (size_t)qrow) * DH
              + quad * 4;
#pragma unroll
    for (int nt = 0; nt < 4; ++nt) *(f32x4*)(ob + 16 * nt) = acc[nt];
    if (quad == 0)
      Lb[(size_t)z * ((size_t)N_B * S_Q) + (size_t)n * S_Q + qrow] = rs;
  } else {
    float* ob = Ob + ((size_t)n * S_Q + (size_t)qrow) * DH + quad * 4;
#pragma unroll
    for (int nt = 0; nt < 4; ++nt)
#pragma unroll
      for (int r = 0; r < 4; ++r)
        atomicAdd(ob + 16 * nt + r, acc[nt][r]);
    if (quad == 0) atomicAdd(&Lb[(size_t)n * S_Q + qrow], rs);
  }
}

// zero O and Lbuf (for atomic mode)
__global__ __launch_bounds__(256)
void sdpa_zero(float* __restrict__ Og, float* __restrict__ Lbuf) {
  constexpr size_t NS = (size_t)N_B * S_Q;
  const size_t i = (size_t)blockIdx.x * 256 + threadIdx.x;
  const f32x4 zz = {0.f, 0.f, 0.f, 0.f};
  ((f32x4*)Og)[i] = zz;
  if (i < NS / 4) ((f32x4*)Lbuf)[i] = zz;
}

// normalize: O[i] /= L[row] (atomic mode)
__global__ __launch_bounds__(256)
void sdpa_norm(float* __restrict__ Og, const float* __restrict__ Lbuf) {
  const size_t i = (size_t)blockIdx.x * 256 + threadIdx.x;
  const size_t qi = i >> 4;
  f32x4 v = ((f32x4*)Og)[i];
  const float inv = 1.0f / Lbuf[qi];
#pragma unroll
  for (int r = 0; r < 4; ++r) v[r] *= inv;
  ((f32x4*)Og)[i] = v;
}

// combine: O = (acc0 + acc1) / (l0 + l1)  (partials mode, r2-proven math)
__global__ __launch_bounds__(256)
void sdpa_combine(const float* __restrict__ ws, float* __restrict__ Og) {
  constexpr size_t NSV = (size_t)N_B * S_Q * DH;
  constexpr size_t NS  = (size_t)N_B * S_Q;
  const size_t i = (size_t)blockIdx.x * 256 + threadIdx.x;
  const f32x4* A0 = (const f32x4*)ws;
  const f32x4* A1 = A0 + NSV / 4;
  const float* L0 = ws + 2 * NSV;
  const float* L1 = L0 + NS;
  const size_t qi = i >> 4;
  const f32x4 a = A0[i], b = A1[i];
  const float inv = 1.0f / (L0[qi] + L1[qi]);
  f32x4 o;
#pragma unroll
  for (int r = 0; r < 4; ++r) o[r] = (a[r] + b[r]) * inv;
  ((f32x4*)Og)[i] = o;
}

// ---- ultimate fallback: reg-staging single-pass (r8-proven structure,
// K-read addressing updated to the new swizzled 128B-row layout)
__global__ __launch_bounds__(512, 4)
void sdpa_fwd_reg(const float* __restrict__ Qg, const float* __restrict__ Kg,
                  const float* __restrict__ Vg, const float* __restrict__ Mg,
                  float* __restrict__ Og)
{
  __shared__ __align__(16) unsigned short ldsK[2][KIMG_B / 2];
  __shared__ __align__(16) unsigned short ldsV[2][VIMG_B / 2];

  const int n = blockIdx.y, q0 = blockIdx.x * BQ, t = threadIdx.x;
  const int w = t >> 6, lane = t & 63, l15 = lane & 15, quad = lane >> 4;
  const int qrow = q0 + w * 16 + l15;

  short8 qf0, qf1;
  {
    const float* qp = Qg + ((size_t)n * S_Q + (size_t)qrow) * DH + quad * 8;
#pragma unroll
    for (int j = 0; j < 8; ++j) {
      qf0[j] = (short)f2bf(qp[j] * QSCALE);
      qf1[j] = (short)f2bf(qp[32 + j] * QSCALE);
    }
  }
  const bool isK = (w < 4);
  const int  tS  = t & 255;
  const float* sgp =
      isK ? Kg + ((size_t)n * S_KV + (size_t)(tS >> 3)) * DH + (tS & 7) * 8
          : Vg + ((size_t)n * S_KV + (size_t)(tS >> 4) * 4) * DH + (tS & 15) * 4;
  const float* mrow = Mg + (size_t)qrow * S_KV + quad * 4;

  const int swz = l15 & 7;
  const int c0 = (quad ^ swz) * 8;
  const int c1 = ((quad + 4) ^ swz) * 8;

  f32x4 acc[4];
#pragma unroll
  for (int nt = 0; nt < 4; ++nt)
#pragma unroll
    for (int r = 0; r < 4; ++r) acc[nt][r] = 0.0f;
  float rs = 0.0f;

  {
    f32x4 L[4];
    if (isK) {
      L[0] = *(const f32x4*)(sgp);
      L[1] = *(const f32x4*)(sgp + 4);
      L[2] = *(const f32x4*)(sgp + 32 * DH);
      L[3] = *(const f32x4*)(sgp + 32 * DH + 4);
      stageK(&ldsK[0][0], L, tS);
    } else {
#pragma unroll
      for (int i = 0; i < 4; ++i) L[i] = *(const f32x4*)(sgp + i * DH);
      stageV(&ldsV[0][0], L, tS);
    }
  }
  __syncthreads();

  for (int it = 0; it < ITERS; ++it) {
    const int p = it & 1, kv0 = it * BK;
    const bool more = (it + 1 < ITERS);
    const unsigned short* kb = &ldsK[p][l15 * KROW];
    short4v pf[4];
#pragma unroll
    for (int h = 0; h < 4; ++h) {
      const short8 kf0 = *(const short8*)(kb + h * 1024 + c0);
      const short8 kf1 = *(const short8*)(kb + h * 1024 + c1);
      const f32x4 mk = *(const f32x4*)(mrow + kv0 + 16 * h);
      f32x4 c = {0.f, 0.f, 0.f, 0.f};
      c = __builtin_amdgcn_mfma_f32_16x16x32_bf16(kf0, qf0, c, 0, 0, 0);
      c = __builtin_amdgcn_mfma_f32_16x16x32_bf16(kf1, qf1, c, 0, 0, 0);
      float e[4];
#pragma unroll
      for (int r = 0; r < 4; ++r)
        e[r] = __builtin_amdgcn_exp2f(fmaf(mk[r], LOG2E, c[r]));
      rs += (e[0] + e[1]) + (e[2] + e[3]);
      union { uint2v u; short4v s; } ue;
      ue.u[0] = packrne(e[0], e[1]);
      ue.u[1] = packrne(e[2], e[3]);
      pf[h] = ue.s;
    }
    f32x4 L[4];
    if (more) {
      const float* np = sgp + (size_t)(kv0 + BK) * DH;
      if (isK) {
        L[0] = *(const f32x4*)(np);
        L[1] = *(const f32x4*)(np + 4);
        L[2] = *(const f32x4*)(np + 32 * DH);
        L[3] = *(const f32x4*)(np + 32 * DH + 4);
      } else {
#pragma unroll
        for (int i = 0; i < 4; ++i) L[i] = *(const f32x4*)(np + i * DH);
      }
    }
#pragma unroll
    for (int nt = 0; nt < 4; ++nt) {
      const int vcol = l15 + 16 * nt;
      const int xr   = (l15 >> 2) + 4 * nt;
#pragma unroll
      for (int h = 0; h < 4; ++h) {
        const int slot = ((4 * h + quad) + xr) & 15;
        short4v vf = *(const short4v*)&ldsV[p][vcol * VSTR + slot * 4];
        acc[nt] = mfma16(vf, pf[h], acc[nt]);
      }
    }
    if (more) {
      if (isK) stageK(&ldsK[p ^ 1][0], L, tS);
      else     stageV(&ldsV[p ^ 1][0], L, tS);
    }
    __syncthreads();
  }

  rs += __shfl_xor(rs, 16, 64);
  rs += __shfl_xor(rs, 32, 64);
  const float inv = 1.0f / rs;
  float* ob = Og + ((size_t)n * S_Q + (size_t)qrow) * DH + quad * 4;
#pragma unroll
  for (int nt = 0; nt < 4; ++nt) {
    f32x4 o;
#pragma unroll
    for (int r = 0; r < 4; ++r) o[r] = acc[nt][r] * inv;
    *(f32x4*)(ob + 16 * nt) = o;
  }
}

extern "C" void kernel_launch(void* const* d_in, const int* in_sizes, int n_in,
                              void* d_out, int out_size, void* d_ws, size_t ws_size,
                              hipStream_t stream) {
  (void)in_sizes; (void)n_in; (void)out_size;
  const float* q = (const float*)d_in[0];
  const float* k = (const float*)d_in[1];
  const float* v = (const float*)d_in[2];
  const float* m = (const float*)d_in[3];
  float* o = (float*)d_out;

  constexpr size_t NSV = (size_t)N_B * S_Q * DH;
  constexpr size_t NS  = (size_t)N_B * S_Q;
  constexpr size_t IMG_BYTES = (size_t)N_B * 64 * TILE_B;            // 17.8 MB
  constexpr size_t PART_BYTES = (2 * NSV + 2 * NS) * sizeof(float);  // 34.1 MB

  // spill tripwire on the high-occupancy build (r8-proven pattern)
  static int use8 = -1;
  if (use8 < 0) {
    hipFuncAttributes attr{};
    use8 = 0;
    if (hipFuncGetAttributes(&attr,
            reinterpret_cast<const void*>(&sdpa_fwd_dma<8>)) == hipSuccess &&
        attr.localSizeBytes == 0)
      use8 = 1;
  }

  if (use8 && d_ws != nullptr && ws_size >= IMG_BYTES + PART_BYTES) {
    // Path A: KV-split x2 (4 blocks/CU) + partials + combine (no atomics)
    unsigned short* imgs = (unsigned short*)d_ws;
    float* part = (float*)((char*)d_ws + IMG_BYTES);
    hipLaunchKernelGGL(sdpa_prep, dim3(N_B * 64), dim3(256), 0, stream,
                       k, v, imgs);
    dim3 grid(S_Q / BQ, N_B, 2);
    hipLaunchKernelGGL((sdpa_fwd_dma<8>), grid, dim3(512), 0, stream,
                       q, m, imgs, part, part + 2 * NSV, ITERS / 2, 1);
    hipLaunchKernelGGL(sdpa_combine, dim3((unsigned)(NSV / 4 / 256)),
                       dim3(256), 0, stream, (const float*)part, o);
  } else if (use8 && d_ws != nullptr &&
             ws_size >= IMG_BYTES + NS * sizeof(float)) {
    // Path A2: KV-split x2 + zero-init + atomicAdd + normalize
    unsigned short* imgs = (unsigned short*)d_ws;
    float* lbuf = (float*)((char*)d_ws + IMG_BYTES);
    hipLaunchKernelGGL(sdpa_prep, dim3(N_B * 64), dim3(256), 0, stream,
                       k, v, imgs);
    hipLaunchKernelGGL(sdpa_zero, dim3((unsigned)(NSV / 4 / 256)), dim3(256),
                       0, stream, o, lbuf);
    dim3 grid(S_Q / BQ, N_B, 2);
    hipLaunchKernelGGL((sdpa_fwd_dma<8>), grid, dim3(512), 0, stream,
                       q, m, imgs, o, lbuf, ITERS / 2, 2);
    hipLaunchKernelGGL(sdpa_norm, dim3((unsigned)(NSV / 4 / 256)), dim3(256),
                       0, stream, o, (const float*)lbuf);
  } else if (d_ws != nullptr && ws_size >= IMG_BYTES) {
    // Path B: single-pass DMA (r10-proven behavior + swizzle)
    unsigned short* imgs = (unsigned short*)d_ws;
    hipLaunchKernelGGL(sdpa_prep, dim3(N_B * 64), dim3(256), 0, stream,
                       k, v, imgs);
    dim3 grid(S_Q / BQ, N_B, 1);
    hipLaunchKernelGGL((sdpa_fwd_dma<4>), grid, dim3(512), 0, stream,
                       q, m, imgs, o, (float*)nullptr, ITERS, 0);
  } else {
    // Path C: reg-staging single-pass
    dim3 grid(S_Q / BQ, N_B);
    hipLaunchKernelGGL(sdpa_fwd_reg, grid, dim3(512), 0, stream,
                       q, k, v, m, o);
  }
}